// Round 4
// baseline (316.687 us; speedup 1.0000x reference)
//
#include <hip/hip_runtime.h>

// GaussianSplatting preprocess — MLP-maximized, LDS-free version.
//   out = concat(positions [N,3], cov [N,3,3], alphas [N], sh [N,4]) flat f32
//   cov = (R S)(R S)^T
// Each thread owns 4 consecutive points, so every per-thread slice is exactly
// float4-tiled: R/S 9xv4f, col/pos 3xv4f, alp 1xv4f, sh 4xv4f, cov 9xv4f.
// 25 v4f loads issue back-to-back (400 B/lane in flight) -> high memory-level
// parallelism, zero barriers, zero LDS. Round-1/3 showed FETCH/WRITE are
// already ideal; the 2.3 TB/s wall was latency-bound, not efficiency-bound.

typedef float v4f __attribute__((ext_vector_type(4)));

#define SH_C0 0.282095f
#define SH_C1 0.488603f
#define BLK 256

__device__ __forceinline__ void cov_from_rs(const float* rq, const float* sq,
                                            float* covq) {
    float tt[9];
#pragma unroll
    for (int a = 0; a < 3; ++a)
#pragma unroll
        for (int c = 0; c < 3; ++c)
            tt[3 * a + c] = rq[3 * a + 0] * sq[0 + c]
                          + rq[3 * a + 1] * sq[3 + c]
                          + rq[3 * a + 2] * sq[6 + c];
#pragma unroll
    for (int a = 0; a < 3; ++a)
#pragma unroll
        for (int c = 0; c < 3; ++c)
            covq[3 * a + c] = tt[3 * a + 0] * tt[3 * c + 0]
                            + tt[3 * a + 1] * tt[3 * c + 1]
                            + tt[3 * a + 2] * tt[3 * c + 2];
}

__global__ __launch_bounds__(BLK) void gs_kernel(
    const float* __restrict__ pos,
    const float* __restrict__ col,
    const float* __restrict__ alp,
    const float* __restrict__ Rm,
    const float* __restrict__ Sm,
    float* __restrict__ out_pos,   // [n*3]
    float* __restrict__ out_cov,   // [n*9]
    float* __restrict__ out_alp,   // [n]
    float* __restrict__ out_sh,    // [n*4]
    int n)
{
    const int g  = blockIdx.x * blockDim.x + threadIdx.x;  // quad index
    const int nq = n >> 2;                                 // full quads

    if (g < nq) {
        const v4f* Rv = (const v4f*)Rm  + (size_t)9 * g;
        const v4f* Sv = (const v4f*)Sm  + (size_t)9 * g;
        const v4f* Cv = (const v4f*)col + (size_t)3 * g;
        const v4f* Pv = (const v4f*)pos + (size_t)3 * g;

        // ---- issue ALL loads up front: 25 outstanding v4f per lane ----
        v4f r[9], s[9], c3[3], p3[3], a1;
#pragma unroll
        for (int k = 0; k < 9; ++k) r[k] = Rv[k];
#pragma unroll
        for (int k = 0; k < 9; ++k) s[k] = Sv[k];
#pragma unroll
        for (int k = 0; k < 3; ++k) c3[k] = Cv[k];
#pragma unroll
        for (int k = 0; k < 3; ++k) p3[k] = Pv[k];
        a1 = ((const v4f*)alp)[g];

        // ---- compute 4 covariances in registers ----
        const float* rf = (const float*)r;
        const float* sf = (const float*)s;
        v4f covq[9];
        float* cf = (float*)covq;
#pragma unroll
        for (int q = 0; q < 4; ++q)
            cov_from_rs(rf + 9 * q, sf + 9 * q, cf + 9 * q);

        // ---- sh for 4 points ----
        const float* cc = (const float*)c3;
        v4f shq[4];
#pragma unroll
        for (int q = 0; q < 4; ++q)
            shq[q] = (v4f){SH_C0,
                           cc[3 * q + 1] * SH_C1,
                           cc[3 * q + 0] * SH_C1,
                           cc[3 * q + 2] * SH_C1};

        // ---- stores: 17 v4f back-to-back ----
        v4f* Ov  = (v4f*)out_cov + (size_t)9 * g;
#pragma unroll
        for (int k = 0; k < 9; ++k) Ov[k] = covq[k];
        v4f* SHv = (v4f*)out_sh + (size_t)4 * g;
#pragma unroll
        for (int k = 0; k < 4; ++k) SHv[k] = shq[k];
        v4f* OPv = (v4f*)out_pos + (size_t)3 * g;
#pragma unroll
        for (int k = 0; k < 3; ++k) OPv[k] = p3[k];
        ((v4f*)out_alp)[g] = a1;
    } else if (g == nq) {
        // tail: up to 3 leftover points, scalar path
        for (int p = nq << 2; p < n; ++p) {
            float rq[9], sq[9], cv[9];
#pragma unroll
            for (int k = 0; k < 9; ++k) rq[k] = Rm[(size_t)9 * p + k];
#pragma unroll
            for (int k = 0; k < 9; ++k) sq[k] = Sm[(size_t)9 * p + k];
            cov_from_rs(rq, sq, cv);
#pragma unroll
            for (int k = 0; k < 9; ++k) out_cov[(size_t)9 * p + k] = cv[k];
            float c0 = col[3 * p + 0], c1 = col[3 * p + 1], c2 = col[3 * p + 2];
            out_sh[(size_t)4 * p + 0] = SH_C0;
            out_sh[(size_t)4 * p + 1] = c1 * SH_C1;
            out_sh[(size_t)4 * p + 2] = c0 * SH_C1;
            out_sh[(size_t)4 * p + 3] = c2 * SH_C1;
            out_pos[3 * p + 0] = pos[3 * p + 0];
            out_pos[3 * p + 1] = pos[3 * p + 1];
            out_pos[3 * p + 2] = pos[3 * p + 2];
            out_alp[p] = alp[p];
        }
    }
}

extern "C" void kernel_launch(void* const* d_in, const int* in_sizes, int n_in,
                              void* d_out, int out_size, void* d_ws, size_t ws_size,
                              hipStream_t stream) {
    const float* pos = (const float*)d_in[0];  // [N,3]
    const float* col = (const float*)d_in[1];  // [N,3]
    const float* alp = (const float*)d_in[2];  // [N]
    const float* Rm  = (const float*)d_in[3];  // [N,3,3]
    const float* Sm  = (const float*)d_in[4];  // [N,3,3]

    int n = in_sizes[0] / 3;

    float* out = (float*)d_out;
    float* out_pos = out;                     // n*3
    float* out_cov = out + (size_t)3 * n;     // n*9
    float* out_alp = out + (size_t)12 * n;    // n
    float* out_sh  = out + (size_t)13 * n;    // n*4

    int nq = n >> 2;
    int total = nq + ((n & 3) ? 1 : 0);
    if (total < 1) total = 1;
    int grid = (total + BLK - 1) / BLK;
    gs_kernel<<<grid, BLK, 0, stream>>>(pos, col, alp, Rm, Sm,
                                        out_pos, out_cov, out_alp, out_sh, n);
}